// Round 5
// baseline (4540.244 us; speedup 1.0000x reference)
//
#include <hip/hip_runtime.h>

typedef _Float16 f16;
typedef _Float16 h2 __attribute__((ext_vector_type(2)));
typedef unsigned int u32;

#define TB  256
#define TTT 2000
#define INW 42
#define HV  24
#define HN  48
#define HD  96
#define NTH 640

// act ring (depth 8), f16 col regions per slot:
// R_N  [0,96):    tmp[0,24) | vadh[24,48) | x[48,90) | pad
// R_NH [96,160):  noih[96,144) | pad
// R_D  [160,288): vadh[160,184) | noih[184,232) | x[232,274) | pad   (matches den_wih col order!)
// R_DH [288,384): denh
#define R_N   0
#define R_NH  96
#define R_D   160
#define R_DH  288
#define ACTW  384

__device__ __forceinline__ float fsigm(float v) {
    return __builtin_amdgcn_rcpf(1.0f + __builtin_amdgcn_exp2f(-1.44269504089f * v));
}
__device__ __forceinline__ float ftanh(float v) {
    float e = __builtin_amdgcn_exp2f(2.88539008178f * v);
    return 1.0f - 2.0f * __builtin_amdgcn_rcpf(e + 1.0f);
}
__device__ __forceinline__ float dot2f(u32 a, u32 w, float c) {
#if __has_builtin(__builtin_amdgcn_fdot2)
    return __builtin_amdgcn_fdot2(__builtin_bit_cast(h2, a), __builtin_bit_cast(h2, w), c, false);
#else
    h2 av = __builtin_bit_cast(h2, a), wv = __builtin_bit_cast(h2, w);
    return c + (float)av[0] * (float)wv[0] + (float)av[1] * (float)wv[1];
#endif
}
__device__ __forceinline__ u32 packw(float a, float b) {
    h2 v; v[0] = (f16)a; v[1] = (f16)b;
    return __builtin_bit_cast(u32, v);
}
template<int CTRL>
__device__ __forceinline__ float dpp_add(float x) {  // quad_perm xor patterns only
    int y = __builtin_amdgcn_mov_dpp(__builtin_bit_cast(int, x), CTRL, 0xF, 0xF, true);
    return x + __builtin_bit_cast(float, y);
}

// raw barrier: flush LDS ops, do NOT drain vmcnt (x prefetch + global stores stay in flight)
#define SYNCB() asm volatile("s_waitcnt lgkmcnt(0)\n\ts_barrier" ::: "memory")

#define ACCI(AV, W, IDX) do { u32 _a = (AV); \
    rr = dot2f(_a, W[0][IDX], rr); zz = dot2f(_a, W[1][IDX], zz); an = dot2f(_a, W[2][IDX], an); } while (0)
#define ACCH(AV, W, IDX) do { u32 _a = (AV); \
    rr = dot2f(_a, W[0][IDX], rr); zz = dot2f(_a, W[1][IDX], zz); hn = dot2f(_a, W[2][IDX], hn); } while (0)
#define ACCI4(U4, W, M0) do { uint4 _u4 = (U4); \
    ACCI(_u4.x, W, (M0)+0); ACCI(_u4.y, W, (M0)+1); ACCI(_u4.z, W, (M0)+2); ACCI(_u4.w, W, (M0)+3); } while (0)
#define ACCH4(U4, W, M0) do { uint4 _u4 = (U4); \
    ACCH(_u4.x, W, (M0)+0); ACCH(_u4.y, W, (M0)+1); ACCH(_u4.z, W, (M0)+2); ACCH(_u4.w, W, (M0)+3); } while (0)
#define OACC4(U4, W, M0) do { uint4 _u4 = (U4); \
    acc = dot2f(_u4.x, W[(M0)+0], acc); acc = dot2f(_u4.y, W[(M0)+1], acc); \
    acc = dot2f(_u4.z, W[(M0)+2], acc); acc = dot2f(_u4.w, W[(M0)+3], acc); } while (0)
#define RED4_Q() do { \
    rr = dpp_add<0xB1>(rr); rr = dpp_add<0x4E>(rr); \
    zz = dpp_add<0xB1>(zz); zz = dpp_add<0x4E>(zz); \
    an = dpp_add<0xB1>(an); an = dpp_add<0x4E>(an); \
    hn = dpp_add<0xB1>(hn); hn = dpp_add<0x4E>(hn); } while (0)
#define RED4_1() do { \
    rr = dpp_add<0xB1>(rr); zz = dpp_add<0xB1>(zz); \
    an = dpp_add<0xB1>(an); hn = dpp_add<0xB1>(hn); } while (0)

template<int N> struct IC { static constexpr int val = N; };

__global__ __launch_bounds__(NTH, 1) void rnnoise_kernel(
    const float* __restrict__ gx,
    const float* __restrict__ in_w,      const float* __restrict__ in_b,
    const float* __restrict__ vad_wih,   const float* __restrict__ vad_whh,
    const float* __restrict__ vad_bih,   const float* __restrict__ vad_bhh,
    const float* __restrict__ vad_out_w, const float* __restrict__ vad_out_b,
    const float* __restrict__ noise_wih, const float* __restrict__ noise_whh,
    const float* __restrict__ noise_bih, const float* __restrict__ noise_bhh,
    const float* __restrict__ den_wih,   const float* __restrict__ den_whh,
    const float* __restrict__ den_bih,   const float* __restrict__ den_bhh,
    const float* __restrict__ out_w,     const float* __restrict__ out_b,
    float* __restrict__ gains, float* __restrict__ vout)
{
    __shared__ __align__(16) f16 act[8][ACTW];   // 6 KB

    const int tid = threadIdx.x, wid = tid >> 6, lane = tid & 63;
    const int b = blockIdx.x;

    #pragma unroll
    for (int i = 0; i < 3; ++i) {
        int idx = tid + i * NTH;
        if (idx < 8 * ACTW / 2) ((u32*)act)[idx] = 0u;
    }
    __syncthreads();

    const bool is_vad = (wid == 9);
    const bool is_noi = (wid == 4 || wid == 5 || wid == 8);

    if (!is_vad && !is_noi) {
        // ======== DEN waves (wid 0,1,2,3,6,7): t = k-5.  wid6: +x-stage+tmp(k). wid7: +out(k-7) ========
        const int dwi = (wid < 4) ? wid : (wid - 2);
        const int u = 16 * dwi + (lane >> 2), q = lane & 3;
        const bool w6 = (wid == 6), w7 = (wid == 7);

        u32 wdi[3][16], wdh[3][12];
        #pragma unroll
        for (int g = 0; g < 3; ++g) {
            const float* wi = den_wih + (g * HD + u) * 114;   // cols [vad|noi|x] == region D order
            #pragma unroll
            for (int m = 0; m < 16; ++m) {
                int c = 32 * q + 2 * m;
                float a  = (c     < 114) ? wi[c]     : 0.f;
                float b2 = (c + 1 < 114) ? wi[c + 1] : 0.f;
                wdi[g][m] = packw(a, b2);
            }
            const float* wh = den_whh + (g * HD + u) * HD + 24 * q;
            #pragma unroll
            for (int m = 0; m < 12; ++m) wdh[g][m] = packw(wh[2*m], wh[2*m+1]);
        }
        const float bdr  = den_bih[u]        + den_bhh[u];
        const float bdz  = den_bih[HD + u]   + den_bhh[HD + u];
        const float bdni = den_bih[2*HD + u];
        const float bdnh = den_bhh[2*HD + u];

        // wid7: out-projection weights (2 lanes per output band)
        const int o = lane >> 1, jo = lane & 1;
        const int oc = (o < 22) ? o : 0;
        u32 wo[24]; float bo = 0.f;
        if (w7) {
            #pragma unroll
            for (int m = 0; m < 24; ++m)
                wo[m] = packw(out_w[oc * HD + 48 * jo + 2*m], out_w[oc * HD + 48 * jo + 2*m + 1]);
            bo = out_b[oc];
        }
        // wid6: tmp weights + x phase regs
        const int ut = (lane < 48) ? (lane >> 1) : 0, q2t = lane & 1;
        u32 wtm[12]; float btm = 0.f;
        float x0=0,x1=0,x2=0,x3=0,x4=0,x5=0,x6=0,x7=0;
        if (w6) {
            #pragma unroll
            for (int m = 0; m < 12; ++m) {
                int c = 24 * q2t + 2 * m;
                float a  = (c     < INW) ? in_w[ut * INW + c]     : 0.f;
                float b2 = (c + 1 < INW) ? in_w[ut * INW + c + 1] : 0.f;
                wtm[m] = packw(a, b2);
            }
            btm = in_b[ut];
            if (lane < INW) {
                x0 = gx[((size_t)b*TTT + 0)*INW + lane]; x1 = gx[((size_t)b*TTT + 1)*INW + lane];
                x2 = gx[((size_t)b*TTT + 2)*INW + lane]; x3 = gx[((size_t)b*TTT + 3)*INW + lane];
                x4 = gx[((size_t)b*TTT + 4)*INW + lane]; x5 = gx[((size_t)b*TTT + 5)*INW + lane];
                x6 = gx[((size_t)b*TTT + 6)*INW + lane]; x7 = gx[((size_t)b*TTT + 7)*INW + lane];
            }
        }
        float hreg = 0.f;
        uint4 pfA0{}, pfA1{}, pfA2{}, pfA3{}, pfB0{}, pfB1{}, pfB2{}, pfB3{};

        auto step = [&](auto PC, int k) {
            constexpr int P = decltype(PC)::val;
            constexpr int SHH = (P + 2) & 7;   // denh(k-6)
            constexpr int SCU = (P + 3) & 7;   // slot of t=k-5 (pf consumed was this slot; denh write)
            constexpr int SPF = (P + 4) & 7;   // prefetch input for t=k-4
            constexpr int SOT = (P + 1) & 7;   // denh(k-7) for out
            if (w6 && k < TTT && lane < INW) {  // stage x(k) into both regions
                float xv;
                if constexpr (P==0) xv=x0; else if constexpr (P==1) xv=x1;
                else if constexpr (P==2) xv=x2; else if constexpr (P==3) xv=x3;
                else if constexpr (P==4) xv=x4; else if constexpr (P==5) xv=x5;
                else if constexpr (P==6) xv=x6; else xv=x7;
                f16 xh = (f16)xv;
                act[P][R_N + 48 + lane] = xh;
                act[P][R_D + 72 + lane] = xh;
            }
            // hh reads (post-barrier, issued first)
            const uint4* hp = (const uint4*)&act[SHH][R_DH + 24 * q];
            uint4 h0 = hp[0], h1 = hp[1], h2 = hp[2];
            // out reads (wid7)
            uint4 e0{}, e1{}, e2{}, e3{}, e4{}, e5{};
            if (w7) {
                const uint4* ep = (const uint4*)&act[SOT][R_DH + 48 * jo];
                e0=ep[0]; e1=ep[1]; e2=ep[2]; e3=ep[3]; e4=ep[4]; e5=ep[5];
            }
            // issue next-tick input prefetch
            {
                const uint4* dp = (const uint4*)&act[SPF][R_D + 32 * q];
                if constexpr ((P & 1) == 0) { pfB0=dp[0]; pfB1=dp[1]; pfB2=dp[2]; pfB3=dp[3]; }
                else                        { pfA0=dp[0]; pfA1=dp[1]; pfA2=dp[2]; pfA3=dp[3]; }
            }
            // input dots from registers (prefetched last tick)
            float rr=0, zz=0, an=0, hn=0;
            {
                uint4 a0=(P&1)?pfB0:pfA0, a1=(P&1)?pfB1:pfA1, a2=(P&1)?pfB2:pfA2, a3=(P&1)?pfB3:pfA3;
                ACCI4(a0, wdi, 0); ACCI4(a1, wdi, 4); ACCI4(a2, wdi, 8); ACCI4(a3, wdi, 12);
            }
            // hh dots (lgkm wait only on h0..h2; pf reads stay outstanding)
            ACCH4(h0, wdh, 0); ACCH4(h1, wdh, 4); ACCH4(h2, wdh, 8);
            RED4_Q();
            if (k >= 5 && k < TTT + 5 && q == 0) {
                float r = fsigm(rr + bdr);
                float z = fsigm(zz + bdz);
                float n = ftanh(an + bdni + r * (hn + bdnh));
                hreg = z * (hreg - n) + n;
                act[SCU][R_DH + u] = (f16)hreg;
            }
            if (w7 && k >= 7 && k < TTT + 7) {   // gains(k-7)
                float acc = 0;
                OACC4(e0, wo, 0); OACC4(e1, wo, 4); OACC4(e2, wo, 8);
                OACC4(e3, wo, 12); OACC4(e4, wo, 16); OACC4(e5, wo, 20);
                acc += __shfl_xor(acc, 1);
                if (jo == 0 && o < 22)
                    gains[((size_t)b * TTT + (k - 7)) * 22 + o] = fsigm(acc + bo);
            }
            if (w6) {
                if (k + 8 < TTT && lane < INW) {   // refill phase reg with x(k+8)
                    float xv = gx[((size_t)b * TTT + (k + 8)) * INW + lane];
                    if constexpr (P==0) x0=xv; else if constexpr (P==1) x1=xv;
                    else if constexpr (P==2) x2=xv; else if constexpr (P==3) x3=xv;
                    else if constexpr (P==4) x4=xv; else if constexpr (P==5) x5=xv;
                    else if constexpr (P==6) x6=xv; else x7=xv;
                }
                if (k < TTT && lane < 48) {        // tmp(k) from x(k) staged this tick (intra-wave)
                    float acc = 0;
                    const uint4* xp = (const uint4*)&act[P][R_N + 48 + 24 * q2t];
                    uint4 a = xp[0], b2 = xp[1], c2 = xp[2];
                    acc=dot2f(a.x,wtm[0],acc);  acc=dot2f(a.y,wtm[1],acc);
                    acc=dot2f(a.z,wtm[2],acc);  acc=dot2f(a.w,wtm[3],acc);
                    acc=dot2f(b2.x,wtm[4],acc); acc=dot2f(b2.y,wtm[5],acc);
                    acc=dot2f(b2.z,wtm[6],acc); acc=dot2f(b2.w,wtm[7],acc);
                    acc=dot2f(c2.x,wtm[8],acc); acc=dot2f(c2.y,wtm[9],acc);
                    acc=dot2f(c2.z,wtm[10],acc);acc=dot2f(c2.w,wtm[11],acc);
                    acc = dpp_add<0xB1>(acc);
                    if (q2t == 0) act[P][R_N + ut] = (f16)ftanh(acc + btm);
                }
            }
            SYNCB();
        };
        #pragma clang loop unroll(disable)
        for (int k0 = 0; k0 < TTT + 8; k0 += 8) {
            step(IC<0>{},k0);   step(IC<1>{},k0+1); step(IC<2>{},k0+2); step(IC<3>{},k0+3);
            step(IC<4>{},k0+4); step(IC<5>{},k0+5); step(IC<6>{},k0+6); step(IC<7>{},k0+7);
        }

    } else if (is_noi) {
        // ======== NOISE waves (wid 4,5,8): t = k-3 ========
        const int nwi = (wid == 4) ? 0 : ((wid == 5) ? 1 : 2);
        const int u = 16 * nwi + (lane >> 2), q = lane & 3;
        u32 wni[3][12], wnh[3][8];
        #pragma unroll
        for (int g = 0; g < 3; ++g) {
            const float* wi = noise_wih + (g * HN + u) * 90;  // cols [tmp|vad|x] == region N order
            #pragma unroll
            for (int m = 0; m < 12; ++m) {
                int c = 24 * q + 2 * m;
                float a  = (c     < 90) ? wi[c]     : 0.f;
                float b2 = (c + 1 < 90) ? wi[c + 1] : 0.f;
                wni[g][m] = packw(a, b2);
            }
            const float* wh = noise_whh + (g * HN + u) * HN;
            #pragma unroll
            for (int m = 0; m < 8; ++m) {
                int c = 16 * q + 2 * m;
                float a  = (c     < 48) ? wh[c]     : 0.f;
                float b2 = (c + 1 < 48) ? wh[c + 1] : 0.f;
                wnh[g][m] = packw(a, b2);
            }
        }
        const float bnr  = noise_bih[u]        + noise_bhh[u];
        const float bnz  = noise_bih[HN + u]   + noise_bhh[HN + u];
        const float bnni = noise_bih[2*HN + u];
        const float bnnh = noise_bhh[2*HN + u];
        float hreg = 0.f;
        uint4 pfA0{}, pfA1{}, pfA2{}, pfB0{}, pfB1{}, pfB2{};

        auto step = [&](auto PC, int k) {
            constexpr int P = decltype(PC)::val;
            constexpr int SHH = (P + 4) & 7;   // noih(k-4)
            constexpr int SCU = (P + 5) & 7;   // slot of t=k-3 (write noih)
            constexpr int SPF = (P + 6) & 7;   // prefetch input for t=k-2
            const uint4* hp = (const uint4*)&act[SHH][R_NH + 16 * q];
            uint4 h0 = hp[0], h1 = hp[1];
            {
                const uint4* np = (const uint4*)&act[SPF][R_N + 24 * q];
                if constexpr ((P & 1) == 0) { pfB0=np[0]; pfB1=np[1]; pfB2=np[2]; }
                else                        { pfA0=np[0]; pfA1=np[1]; pfA2=np[2]; }
            }
            float rr=0, zz=0, an=0, hn=0;
            {
                uint4 a0=(P&1)?pfB0:pfA0, a1=(P&1)?pfB1:pfA1, a2=(P&1)?pfB2:pfA2;
                ACCI4(a0, wni, 0); ACCI4(a1, wni, 4); ACCI4(a2, wni, 8);
            }
            ACCH4(h0, wnh, 0); ACCH4(h1, wnh, 4);
            RED4_Q();
            if (k >= 3 && k < TTT + 3 && q == 0) {
                float r = fsigm(rr + bnr);
                float z = fsigm(zz + bnz);
                float n = ftanh(an + bnni + r * (hn + bnnh));
                hreg = z * (hreg - n) + n;
                f16 hh = (f16)hreg;
                act[SCU][R_NH + u]     = hh;
                act[SCU][R_D + 24 + u] = hh;
            }
            SYNCB();
        };
        #pragma clang loop unroll(disable)
        for (int k0 = 0; k0 < TTT + 8; k0 += 8) {
            step(IC<0>{},k0);   step(IC<1>{},k0+1); step(IC<2>{},k0+2); step(IC<3>{},k0+3);
            step(IC<4>{},k0+4); step(IC<5>{},k0+5); step(IC<6>{},k0+6); step(IC<7>{},k0+7);
        }

    } else {
        // ======== VAD wave (wid 9): vad GRU t = k-1, vad_out(k-1) ========
        const int uv = (lane < 48) ? (lane >> 1) : 0, q2 = lane & 1;
        u32 wvi[3][6], wvh[3][6];
        float bvr=0, bvz=0, bvni=0, bvnh=0, wvo_u=0;
        if (lane < 48) {
            #pragma unroll
            for (int g = 0; g < 3; ++g) {
                const float* wi = vad_wih + (g * HV + uv) * HV + 12 * q2;
                const float* wh = vad_whh + (g * HV + uv) * HV + 12 * q2;
                #pragma unroll
                for (int j = 0; j < 6; ++j) {
                    wvi[g][j] = packw(wi[2*j], wi[2*j+1]);
                    wvh[g][j] = packw(wh[2*j], wh[2*j+1]);
                }
            }
            bvr  = vad_bih[uv]        + vad_bhh[uv];
            bvz  = vad_bih[HV + uv]   + vad_bhh[HV + uv];
            bvni = vad_bih[2*HV + uv];
            bvnh = vad_bhh[2*HV + uv];
            if (q2 == 0) wvo_u = vad_out_w[uv];
        }
        const float bvo = vad_out_b[0];
        float hreg = 0.f;

        auto step = [&](auto PC, int k) {
            constexpr int P = decltype(PC)::val;
            constexpr int ST  = (P + 7) & 7;   // slot of t=k-1 (tmp read, vadh write)
            constexpr int SVH = (P + 6) & 7;   // vadh(k-2)
            if (k >= 1 && k <= TTT) {
                float rr=0, zz=0, an=0, hn=0;
                if (lane < 48) {
                    const uint2* tp = (const uint2*)&act[ST][R_N + 12 * q2];
                    const uint2* hp = (const uint2*)&act[SVH][R_N + 24 + 12 * q2];
                    #pragma unroll
                    for (int v = 0; v < 3; ++v) {
                        uint2 a = tp[v]; ACCI(a.x, wvi, 2*v); ACCI(a.y, wvi, 2*v+1);
                        uint2 h = hp[v]; ACCH(h.x, wvh, 2*v); ACCH(h.y, wvh, 2*v+1);
                    }
                    RED4_1();
                    if (q2 == 0) {
                        float r = fsigm(rr + bvr);
                        float z = fsigm(zz + bvz);
                        float n = ftanh(an + bvni + r * (hn + bvnh));
                        hreg = z * (hreg - n) + n;
                        f16 hh = (f16)hreg;
                        act[ST][R_N + 24 + uv] = hh;
                        act[ST][R_D + uv]      = hh;
                    }
                }
                float val = (lane < 48 && q2 == 0) ? (wvo_u * hreg) : 0.f;
                val = dpp_add<0xB1>(val); val = dpp_add<0x4E>(val);
                val += __shfl_xor(val, 4);  val += __shfl_xor(val, 8);
                val += __shfl_xor(val, 16); val += __shfl_xor(val, 32);
                if (lane == 0) vout[(size_t)b * TTT + (k - 1)] = fsigm(val + bvo);
            }
            SYNCB();
        };
        #pragma clang loop unroll(disable)
        for (int k0 = 0; k0 < TTT + 8; k0 += 8) {
            step(IC<0>{},k0);   step(IC<1>{},k0+1); step(IC<2>{},k0+2); step(IC<3>{},k0+3);
            step(IC<4>{},k0+4); step(IC<5>{},k0+5); step(IC<6>{},k0+6); step(IC<7>{},k0+7);
        }
    }
}

extern "C" void kernel_launch(void* const* d_in, const int* in_sizes, int n_in,
                              void* d_out, int out_size, void* d_ws, size_t ws_size,
                              hipStream_t stream) {
    (void)in_sizes; (void)n_in; (void)d_ws; (void)ws_size; (void)out_size;
    const float* gx        = (const float*)d_in[0];
    const float* in_w      = (const float*)d_in[1];
    const float* in_b      = (const float*)d_in[2];
    const float* vad_wih   = (const float*)d_in[3];
    const float* vad_whh   = (const float*)d_in[4];
    const float* vad_bih   = (const float*)d_in[5];
    const float* vad_bhh   = (const float*)d_in[6];
    const float* vad_out_w = (const float*)d_in[7];
    const float* vad_out_b = (const float*)d_in[8];
    const float* noise_wih = (const float*)d_in[9];
    const float* noise_whh = (const float*)d_in[10];
    const float* noise_bih = (const float*)d_in[11];
    const float* noise_bhh = (const float*)d_in[12];
    const float* den_wih   = (const float*)d_in[13];
    const float* den_whh   = (const float*)d_in[14];
    const float* den_bih   = (const float*)d_in[15];
    const float* den_bhh   = (const float*)d_in[16];
    const float* out_w     = (const float*)d_in[17];
    const float* out_b     = (const float*)d_in[18];
    float* gains = (float*)d_out;
    float* vout  = (float*)d_out + (size_t)TB * (size_t)TTT * 22;

    rnnoise_kernel<<<dim3(TB), dim3(NTH), 0, stream>>>(
        gx, in_w, in_b, vad_wih, vad_whh, vad_bih, vad_bhh, vad_out_w, vad_out_b,
        noise_wih, noise_whh, noise_bih, noise_bhh, den_wih, den_whh, den_bih, den_bhh,
        out_w, out_b, gains, vout);
}

// Round 6
// 1892.916 us; speedup vs baseline: 2.3985x; 2.3985x over previous
//
#include <hip/hip_runtime.h>

typedef _Float16 f16;
typedef _Float16 h2 __attribute__((ext_vector_type(2)));
typedef unsigned int u32;

#define TB  256
#define TTT 2000
#define INW 42
#define HV  24
#define HN  48
#define HD  96
#define NTH 640

// act ring (depth 4), f16 regions per slot (all 16B-aligned):
// DIN [0,128):   vadh[0,24) | noih[24,72) | x[72,114) | pad       == den_wih col order
// DH  [128,224): denh
// NIN [224,320): tmp[224,248) | vadh[248,272) | x[272,314) | pad  == noise_wih col order
// NH  [320,384): noih[320,368) | pad
#define DIN 0
#define DH  128
#define NIN 224
#define NH  320
#define ACTW 384

__device__ __forceinline__ float fsigm(float v) {
    return __builtin_amdgcn_rcpf(1.0f + __builtin_amdgcn_exp2f(-1.44269504089f * v));
}
__device__ __forceinline__ float ftanh(float v) {
    float e = __builtin_amdgcn_exp2f(2.88539008178f * v);
    return 1.0f - 2.0f * __builtin_amdgcn_rcpf(e + 1.0f);
}
__device__ __forceinline__ float dot2f(u32 a, u32 w, float c) {
#if __has_builtin(__builtin_amdgcn_fdot2)
    return __builtin_amdgcn_fdot2(__builtin_bit_cast(h2, a), __builtin_bit_cast(h2, w), c, false);
#else
    h2 av = __builtin_bit_cast(h2, a), wv = __builtin_bit_cast(h2, w);
    return c + (float)av[0] * (float)wv[0] + (float)av[1] * (float)wv[1];
#endif
}
__device__ __forceinline__ u32 packw(float a, float b) {
    h2 v; v[0] = (f16)a; v[1] = (f16)b;
    return __builtin_bit_cast(u32, v);
}
// DPP adds. xor quad_perm (0xB1, 0x4E) for partial-group sums (direction-free).
// row_ror:4/8 (0x124/0x128) ONLY after quad sums, to build FULL 16-lane row sums
// (rotate-accumulate gives every lane the complete row total; direction irrelevant).
template<int CTRL>
__device__ __forceinline__ float dpp_add(float x) {
    int y = __builtin_amdgcn_mov_dpp(__builtin_bit_cast(int, x), CTRL, 0xF, 0xF, true);
    return x + __builtin_bit_cast(float, y);
}

// raw barrier: flush LDS ops, do NOT drain vmcnt (x prefetch + global stores stay in flight)
#define SYNCB() asm volatile("s_waitcnt lgkmcnt(0)\n\ts_barrier" ::: "memory")

#define ACCI(AV, W, IDX) do { u32 _a = (AV); \
    rr = dot2f(_a, W[0][IDX], rr); zz = dot2f(_a, W[1][IDX], zz); an = dot2f(_a, W[2][IDX], an); } while (0)
#define ACCH(AV, W, IDX) do { u32 _a = (AV); \
    rr = dot2f(_a, W[0][IDX], rr); zz = dot2f(_a, W[1][IDX], zz); hn = dot2f(_a, W[2][IDX], hn); } while (0)
#define ACCI4(U4, W, M0) do { uint4 _u4 = (U4); \
    ACCI(_u4.x, W, (M0)+0); ACCI(_u4.y, W, (M0)+1); ACCI(_u4.z, W, (M0)+2); ACCI(_u4.w, W, (M0)+3); } while (0)
#define ACCH4(U4, W, M0) do { uint4 _u4 = (U4); \
    ACCH(_u4.x, W, (M0)+0); ACCH(_u4.y, W, (M0)+1); ACCH(_u4.z, W, (M0)+2); ACCH(_u4.w, W, (M0)+3); } while (0)
#define RED4_Q() do { \
    rr = dpp_add<0xB1>(rr); rr = dpp_add<0x4E>(rr); \
    zz = dpp_add<0xB1>(zz); zz = dpp_add<0x4E>(zz); \
    an = dpp_add<0xB1>(an); an = dpp_add<0x4E>(an); \
    hn = dpp_add<0xB1>(hn); hn = dpp_add<0x4E>(hn); } while (0)
#define RED4_1() do { \
    rr = dpp_add<0xB1>(rr); zz = dpp_add<0xB1>(zz); \
    an = dpp_add<0xB1>(an); hn = dpp_add<0xB1>(hn); } while (0)

template<int N> struct IC { static constexpr int val = N; };

__global__ __launch_bounds__(NTH, 2) void rnnoise_kernel(
    const float* __restrict__ gx,
    const float* __restrict__ in_w,      const float* __restrict__ in_b,
    const float* __restrict__ vad_wih,   const float* __restrict__ vad_whh,
    const float* __restrict__ vad_bih,   const float* __restrict__ vad_bhh,
    const float* __restrict__ vad_out_w, const float* __restrict__ vad_out_b,
    const float* __restrict__ noise_wih, const float* __restrict__ noise_whh,
    const float* __restrict__ noise_bih, const float* __restrict__ noise_bhh,
    const float* __restrict__ den_wih,   const float* __restrict__ den_whh,
    const float* __restrict__ den_bih,   const float* __restrict__ den_bhh,
    const float* __restrict__ out_w,     const float* __restrict__ out_b,
    float* __restrict__ gains, float* __restrict__ vout)
{
    __shared__ __align__(16) f16 act[4][ACTW];   // 3 KB

    const int tid = threadIdx.x, wid = tid >> 6, lane = tid & 63;
    const int b = blockIdx.x;

    // zero everything (initial states AND pads; pads are never written again)
    if (tid < 768) ((u32*)act)[tid] = 0u;
    if (tid + NTH < 768) ((u32*)act)[tid + NTH] = 0u;
    __syncthreads();

    // role map (round-3 proven): den on wid {0,1,2,3,6,7}, noise {4,5,8}, vad {9}
    const int role = (wid == 9) ? 2 : ((wid == 4 || wid == 5 || wid == 8) ? 1 : 0);

    if (role == 0) {
        // ================== DEN: t = k-3 at tick k (16 units/wave, 4-lane teams) ==================
        const int dwi = (wid < 4) ? wid : (wid - 2);       // 0..5
        const int u = 16 * dwi + (lane >> 2), q = lane & 3;
        u32 wdi[3][16], wdh[3][12];
        #pragma unroll
        for (int g = 0; g < 3; ++g) {
            const float* wi = den_wih + (g * HD + u) * 114;   // cols [vad|noi|x] == DIN order
            #pragma unroll
            for (int m = 0; m < 16; ++m) {
                int c = 32 * q + 2 * m;                       // DIN dim
                float a  = (c     < 114) ? wi[c]     : 0.f;
                float b2 = (c + 1 < 114) ? wi[c + 1] : 0.f;
                wdi[g][m] = packw(a, b2);
            }
            const float* wh = den_whh + (g * HD + u) * HD + 24 * q;
            #pragma unroll
            for (int m = 0; m < 12; ++m) wdh[g][m] = packw(wh[2*m], wh[2*m+1]);
        }
        const float bdr  = den_bih[u]        + den_bhh[u];
        const float bdz  = den_bih[HD + u]   + den_bhh[HD + u];
        const float bdni = den_bih[2*HD + u];
        const float bdnh = den_bhh[2*HD + u];
        float hreg = 0.f;

        auto step = [&](auto PC, int k) {
            constexpr int P  = decltype(PC)::val;
            constexpr int SI = (P + 1) & 3;   // slot of t=k-3 (inputs; denh write)
            if (k >= 3 && k <= TTT + 2) {
                float rr = 0, zz = 0, an = 0, hn = 0;
                const uint4* hp = (const uint4*)&act[P][DH + 24 * q];    // denh(t-1)
                uint4 h0 = hp[0], h1 = hp[1], h2 = hp[2];
                const uint4* ip = (const uint4*)&act[SI][DIN + 32 * q];  // [vadh|noih|x]
                uint4 a0 = ip[0], a1 = ip[1], a2 = ip[2], a3 = ip[3];
                ACCI4(a0, wdi, 0); ACCI4(a1, wdi, 4); ACCI4(a2, wdi, 8); ACCI4(a3, wdi, 12);
                ACCH4(h0, wdh, 0); ACCH4(h1, wdh, 4); ACCH4(h2, wdh, 8);
                RED4_Q();
                if (q == 0) {
                    float r = fsigm(rr + bdr);
                    float z = fsigm(zz + bdz);
                    float n = ftanh(an + bdni + r * (hn + bdnh));
                    hreg = z * (hreg - n) + n;
                    act[SI][DH + u] = (f16)hreg;
                }
            }
            SYNCB();
        };
        #pragma clang loop unroll(disable)
        for (int k0 = 0; k0 < TTT + 4; k0 += 4) {
            step(IC<0>{}, k0); step(IC<1>{}, k0+1); step(IC<2>{}, k0+2); step(IC<3>{}, k0+3);
        }

    } else if (role == 1) {
        // ====== NOISE: t = k-2 at tick k (16 units/wave, 4-lane teams); OUT: t = k-4 ======
        const int nwi = (wid == 4) ? 0 : ((wid == 5) ? 1 : 2);
        const int u = 16 * nwi + (lane >> 2), q = lane & 3;
        const int o = 8 * nwi + (lane >> 3), s8 = lane & 7;
        const int oc = (o < 22) ? o : 0;
        u32 wni[3][12], wnh[3][8], wo[6];
        #pragma unroll
        for (int g = 0; g < 3; ++g) {
            const float* wi = noise_wih + (g * HN + u) * 90;   // cols [tmp|vad|x] == NIN order
            #pragma unroll
            for (int m = 0; m < 12; ++m) {
                int c = 24 * q + 2 * m;
                float a  = (c     < 90) ? wi[c]     : 0.f;
                float b2 = (c + 1 < 90) ? wi[c + 1] : 0.f;
                wni[g][m] = packw(a, b2);
            }
            const float* wh = noise_whh + (g * HN + u) * HN;
            #pragma unroll
            for (int m = 0; m < 8; ++m) {
                int c = 16 * q + 2 * m;                        // NH dim (pad -> 0 weight)
                float a  = (c     < 48) ? wh[c]     : 0.f;
                float b2 = (c + 1 < 48) ? wh[c + 1] : 0.f;
                wnh[g][m] = packw(a, b2);
            }
        }
        #pragma unroll
        for (int m = 0; m < 6; ++m)
            wo[m] = packw(out_w[oc*HD + 12*s8 + 2*m], out_w[oc*HD + 12*s8 + 2*m + 1]);
        const float bnr  = noise_bih[u]        + noise_bhh[u];
        const float bnz  = noise_bih[HN + u]   + noise_bhh[HN + u];
        const float bnni = noise_bih[2*HN + u];
        const float bnnh = noise_bhh[2*HN + u];
        const float bo   = out_b[oc];
        float hreg = 0.f;

        auto step = [&](auto PC, int k) {
            constexpr int P   = decltype(PC)::val;
            constexpr int SI  = (P + 2) & 3;   // slot of t=k-2 (inputs; noih write)
            constexpr int SH  = (P + 1) & 3;   // noih(t-1)
            if (k >= 2 && k <= TTT + 1) {
                float rr = 0, zz = 0, an = 0, hn = 0;
                const uint4* hp = (const uint4*)&act[SH][NH + 16 * q];
                uint4 h0 = hp[0], h1 = hp[1];
                const uint4* ip = (const uint4*)&act[SI][NIN + 24 * q];
                uint4 a0 = ip[0], a1 = ip[1], a2 = ip[2];
                ACCI4(a0, wni, 0); ACCI4(a1, wni, 4); ACCI4(a2, wni, 8);
                ACCH4(h0, wnh, 0); ACCH4(h1, wnh, 4);
                RED4_Q();
                if (q == 0) {
                    float r = fsigm(rr + bnr);
                    float z = fsigm(zz + bnz);
                    float n = ftanh(an + bnni + r * (hn + bnnh));
                    hreg = z * (hreg - n) + n;
                    f16 hh = (f16)hreg;
                    act[SI][NH + u]       = hh;   // noise hh source
                    act[SI][DIN + 24 + u] = hh;   // den input copy
                }
            }
            if (k >= 4) {   // gains(t=k-4) over denh(k-4) in slot P
                float acc = 0;
                const uint2* dp = (const uint2*)&act[P][DH + 12 * s8];
                uint2 d0 = dp[0], d1 = dp[1], d2 = dp[2];
                acc = dot2f(d0.x, wo[0], acc); acc = dot2f(d0.y, wo[1], acc);
                acc = dot2f(d1.x, wo[2], acc); acc = dot2f(d1.y, wo[3], acc);
                acc = dot2f(d2.x, wo[4], acc); acc = dot2f(d2.y, wo[5], acc);
                acc = dpp_add<0xB1>(acc); acc = dpp_add<0x4E>(acc);
                acc += __shfl_xor(acc, 4);
                if (s8 == 0 && o < 22)
                    gains[((size_t)b * TTT + (k - 4)) * 22 + o] = fsigm(acc + bo);
            }
            SYNCB();
        };
        #pragma clang loop unroll(disable)
        for (int k0 = 0; k0 < TTT + 4; k0 += 4) {
            step(IC<0>{}, k0); step(IC<1>{}, k0+1); step(IC<2>{}, k0+2); step(IC<3>{}, k0+3);
        }

    } else {
        // ====== VAD wave: x stage + tmp(k) + vad GRU(t=k-1) + vad_out(t=k-1) ======
        const int l = lane;
        const int u = (l < 48) ? (l >> 1) : 0, q2 = l & 1;
        u32 wvi[3][6], wvh[3][6], wtm[12];
        float bvr = 0, bvz = 0, bvni = 0, bvnh = 0, btm = 0, wvo_u = 0;
        if (l < 48) {
            #pragma unroll
            for (int g = 0; g < 3; ++g) {
                const float* wi = vad_wih + (g * HV + u) * HV + 12 * q2;
                const float* wh = vad_whh + (g * HV + u) * HV + 12 * q2;
                #pragma unroll
                for (int j = 0; j < 6; ++j) {
                    wvi[g][j] = packw(wi[2*j], wi[2*j+1]);
                    wvh[g][j] = packw(wh[2*j], wh[2*j+1]);
                }
            }
            #pragma unroll
            for (int j = 0; j < 12; ++j) {
                int c0 = 24 * q2 + 2 * j;                     // NIN x dim (pad -> 0 weight)
                float a = (c0     < INW) ? in_w[u * INW + c0]     : 0.f;
                float c = (c0 + 1 < INW) ? in_w[u * INW + c0 + 1] : 0.f;
                wtm[j] = packw(a, c);
            }
            bvr  = vad_bih[u]        + vad_bhh[u];
            bvz  = vad_bih[HV + u]   + vad_bhh[HV + u];
            bvni = vad_bih[2*HV + u];
            bvnh = vad_bhh[2*HV + u];
            btm  = in_b[u];
            if (q2 == 0) wvo_u = vad_out_w[u];
        }
        const float bvo = vad_out_b[0];
        float hreg = 0.f;

        float xa = 0, xb = 0, xc = 0, xd = 0;
        if (l < INW) {
            xa = gx[((size_t)b * TTT + 0) * INW + l];
            xb = gx[((size_t)b * TTT + 1) * INW + l];
            xc = gx[((size_t)b * TTT + 2) * INW + l];
            xd = gx[((size_t)b * TTT + 3) * INW + l];
        }

        auto step = [&](auto PC, int k) {
            constexpr int P  = decltype(PC)::val;
            constexpr int ST = (P + 3) & 3;   // slot of t=k-1 (tmp read, vadh write)
            constexpr int SH = (P + 2) & 3;   // vadh(k-2)
            if (k < TTT && l < INW) {         // stage x(k) into both regions of slot P
                float xv;
                if constexpr (P == 0) xv = xa; else if constexpr (P == 1) xv = xb;
                else if constexpr (P == 2) xv = xc; else xv = xd;
                f16 xh = (f16)xv;
                act[P][NIN + 48 + l] = xh;
                act[P][DIN + 72 + l] = xh;
            }
            if (k + 4 < TTT && l < INW) {     // refill phase register with x(k+4)
                float xv = gx[((size_t)b * TTT + (k + 4)) * INW + l];
                if constexpr (P == 0) xa = xv; else if constexpr (P == 1) xb = xv;
                else if constexpr (P == 2) xc = xv; else xd = xv;
            }
            if (k >= 1 && k <= TTT) {         // vad GRU t = k-1
                float rr = 0, zz = 0, an = 0, hn = 0;
                if (l < 48) {
                    const uint2* tp = (const uint2*)&act[ST][NIN + 12 * q2];       // tmp(t)
                    const uint2* hp = (const uint2*)&act[SH][NIN + 24 + 12 * q2];  // vadh(t-1)
                    #pragma unroll
                    for (int v = 0; v < 3; ++v) {
                        uint2 a = tp[v]; ACCI(a.x, wvi, 2*v); ACCI(a.y, wvi, 2*v+1);
                        uint2 h = hp[v]; ACCH(h.x, wvh, 2*v); ACCH(h.y, wvh, 2*v+1);
                    }
                    RED4_1();
                    if (q2 == 0) {
                        float r = fsigm(rr + bvr);
                        float z = fsigm(zz + bvz);
                        float n = ftanh(an + bvni + r * (hn + bvnh));
                        hreg = z * (hreg - n) + n;
                        f16 hh = (f16)hreg;
                        act[ST][NIN + 24 + u] = hh;   // noise/vad hh source
                        act[ST][DIN + u]      = hh;   // den input copy
                    }
                }
                // vad_out(t): full-wave reduce. quad xor DPP, then FULL-row ror DPP,
                // then 2 direction-free shfl_xor for cross-row.
                float val = (l < 48 && q2 == 0) ? (wvo_u * hreg) : 0.f;
                val = dpp_add<0xB1>(val);  val = dpp_add<0x4E>(val);
                val = dpp_add<0x124>(val); val = dpp_add<0x128>(val);   // full 16-row sum
                val += __shfl_xor(val, 16); val += __shfl_xor(val, 32);
                if (l == 0) vout[(size_t)b * TTT + (k - 1)] = fsigm(val + bvo);
            }
            if (k < TTT && l < 48) {          // tmp(k) from x(k) staged this tick (intra-wave)
                float acc = 0;
                const uint4* xp = (const uint4*)&act[P][NIN + 48 + 24 * q2];
                uint4 a = xp[0], b2 = xp[1], c2 = xp[2];
                acc = dot2f(a.x,  wtm[0], acc);  acc = dot2f(a.y,  wtm[1], acc);
                acc = dot2f(a.z,  wtm[2], acc);  acc = dot2f(a.w,  wtm[3], acc);
                acc = dot2f(b2.x, wtm[4], acc);  acc = dot2f(b2.y, wtm[5], acc);
                acc = dot2f(b2.z, wtm[6], acc);  acc = dot2f(b2.w, wtm[7], acc);
                acc = dot2f(c2.x, wtm[8], acc);  acc = dot2f(c2.y, wtm[9], acc);
                acc = dot2f(c2.z, wtm[10], acc); acc = dot2f(c2.w, wtm[11], acc);
                acc = dpp_add<0xB1>(acc);
                if (q2 == 0) act[P][NIN + u] = (f16)ftanh(acc + btm);
            }
            SYNCB();
        };
        #pragma clang loop unroll(disable)
        for (int k0 = 0; k0 < TTT + 4; k0 += 4) {
            step(IC<0>{}, k0); step(IC<1>{}, k0+1); step(IC<2>{}, k0+2); step(IC<3>{}, k0+3);
        }
    }
}

extern "C" void kernel_launch(void* const* d_in, const int* in_sizes, int n_in,
                              void* d_out, int out_size, void* d_ws, size_t ws_size,
                              hipStream_t stream) {
    (void)in_sizes; (void)n_in; (void)d_ws; (void)ws_size; (void)out_size;
    const float* gx        = (const float*)d_in[0];
    const float* in_w      = (const float*)d_in[1];
    const float* in_b      = (const float*)d_in[2];
    const float* vad_wih   = (const float*)d_in[3];
    const float* vad_whh   = (const float*)d_in[4];
    const float* vad_bih   = (const float*)d_in[5];
    const float* vad_bhh   = (const float*)d_in[6];
    const float* vad_out_w = (const float*)d_in[7];
    const float* vad_out_b = (const float*)d_in[8];
    const float* noise_wih = (const float*)d_in[9];
    const float* noise_whh = (const float*)d_in[10];
    const float* noise_bih = (const float*)d_in[11];
    const float* noise_bhh = (const float*)d_in[12];
    const float* den_wih   = (const float*)d_in[13];
    const float* den_whh   = (const float*)d_in[14];
    const float* den_bih   = (const float*)d_in[15];
    const float* den_bhh   = (const float*)d_in[16];
    const float* out_w     = (const float*)d_in[17];
    const float* out_b     = (const float*)d_in[18];
    float* gains = (float*)d_out;
    float* vout  = (float*)d_out + (size_t)TB * (size_t)TTT * 22;

    rnnoise_kernel<<<dim3(TB), dim3(NTH), 0, stream>>>(
        gx, in_w, in_b, vad_wih, vad_whh, vad_bih, vad_bhh, vad_out_w, vad_out_b,
        noise_wih, noise_whh, noise_bih, noise_bhh, den_wih, den_whh, den_bih, den_bhh,
        out_w, out_b, gains, vout);
}